// Round 14
// baseline (271.421 us; speedup 1.0000x reference)
//
#include <hip/hip_runtime.h>
#include <cstdint>
#include <cstddef>

typedef __attribute__((ext_vector_type(8))) short short8;
typedef __attribute__((ext_vector_type(4))) float f32x4;

#define B_ROWS 65536
#define DMODEL 2048
#define NEXP 64
#define TOPK 8
#define THREADS 256                      // 4 waves; wave = 16 rows x 64 experts
#define ROWS_PER_BLK 64
#define NBLK (B_ROWS / ROWS_PER_BLK)     // 1024 blocks = 2 per CU (LDS-bound)
#define NKS (DMODEL / 32)                // 64 k-steps
#define NSC 16                           // superchunks of 4 ks (512B/row)
#define XW 2080                          // floats per SC buffer per wave (8x260)
#define SLAB 67
#define GOFF ((size_t)B_ROWS * NEXP)
#define AUX_OFF (GOFF + (size_t)B_ROWS * TOPK)
#define WS_FRAG_OFF 131072               // float offset of W-frag region in ws
#define WS2_OFF 229376                   // float offset of aux1 partials

#define GLOAD16(g, l)                                                      \
  __builtin_amdgcn_global_load_lds(                                       \
      (const __attribute__((address_space(1))) void*)(g),                 \
      (__attribute__((address_space(3))) void*)(l), 16, 0, 0)

// R9/R11-proven RNE bf16 helper
__device__ __forceinline__ unsigned short bf16_rne(float v, float* back) {
  unsigned u = __float_as_uint(v);
  unsigned r = (u + 0x7FFFu + ((u >> 16) & 1u)) >> 16;
  *back = __uint_as_float(r << 16);
  return (unsigned short)r;
}

// W -> bf16x3 B-fragments (R11 verbatim)
__global__ __launch_bounds__(256) void router_prep(
    const float* __restrict__ W, unsigned short* __restrict__ frag)
{
  const int ks = blockIdx.x;
  const int nt = threadIdx.x >> 6;
  const int lane = threadIdx.x & 63;
  const int krow = ks * 32 + (lane >> 4) * 8;
  const int col = nt * 16 + (lane & 15);
  short8 hv, mv, lv;
#pragma unroll
  for (int j = 0; j < 8; ++j) {
    float v = W[(size_t)(krow + j) * NEXP + col];
    float fh, fm, fl;
    unsigned short h = bf16_rne(v, &fh);
    float r = v - fh;
    unsigned short m = bf16_rne(r, &fm);
    float r2 = r - fm;
    unsigned short l = bf16_rne(r2, &fl);
    hv[j] = (short)h; mv[j] = (short)m; lv[j] = (short)l;
  }
  size_t base = (size_t)(ks * 4 + nt) * 1536 + lane * 8;
  *(short8*)(frag + base)        = hv;
  *(short8*)(frag + base + 512)  = mv;
  *(short8*)(frag + base + 1024) = lv;
}

// R11 cvt3 verbatim
__device__ __forceinline__ void cvt3(float4 a, float4 b,
                                     short8* H, short8* M, short8* L) {
  float f[8] = {a.x, a.y, a.z, a.w, b.x, b.y, b.z, b.w};
#pragma unroll
  for (int j = 0; j < 8; ++j) {
    float fh, fm, fl;
    unsigned short h = bf16_rne(f[j], &fh);
    float r = f[j] - fh;
    unsigned short m = bf16_rne(r, &fm);
    float r2 = r - fm;
    unsigned short l = bf16_rne(r2, &fl);
    (*H)[j] = (short)h; (*M)[j] = (short)m; (*L)[j] = (short)l;
  }
}

#define MFMA __builtin_amdgcn_mfma_f32_16x16x32_bf16

__global__ __launch_bounds__(THREADS, 2) void router_main(
    const float* __restrict__ x, const float* __restrict__ bias,
    const unsigned short* __restrict__ frag, float* __restrict__ out,
    float* __restrict__ ws)
{
  // LDS: x superchunk double-buffer, wave-private: [4 waves][2 bufs][2080].
  // Epilogue slab [64][67] overlays it after a barrier.
  __shared__ __align__(16) float lds[4 * 2 * XW];

  const int tid = threadIdx.x;
  const int lane = tid & 63;
  const int w = tid >> 6;
  const size_t row0 = (size_t)blockIdx.x * ROWS_PER_BLK;

  f32x4 acc[4];
#pragma unroll
  for (int nt = 0; nt < 4; ++nt) acc[nt] = (f32x4){0.f, 0.f, 0.f, 0.f};

  // x gload: instr i reads rows 2i,2i+1 of this wave, 512B contiguous per
  // half-wave: lane l -> row 2i+(l>>5), float col (l&31)*4 within SC window.
  const float* xg = x + (row0 + (size_t)w * 16 + (lane >> 5)) * DMODEL
                  + (lane & 31) * 4;
  // LDS read base: row r=lane&15 at (r>>1)*260 + (r&1)*128; k-col (l>>4)*8.
  // Bank spread: pair p at start-quad 4p -> 8 quads x 2-way = conflict-free.
  const int xrbase = w * (2 * XW) + ((lane & 15) >> 1) * 260
                   + ((lane & 15) & 1) * 128 + (lane >> 4) * 8;

#define STAGE_X(SC, BUF)                                                   \
  do {                                                                     \
    _Pragma("unroll") for (int i = 0; i < 8; ++i)                          \
      GLOAD16(xg + (size_t)i * 2 * DMODEL + (SC) * 128,                    \
              lds + w * (2 * XW) + (BUF) * XW + i * 260);                  \
  } while (0)

#define LOAD_B(KS, NT, BH, BM, BL)                                         \
  do {                                                                     \
    const short8* fb_ = (const short8*)(frag + (size_t)((KS) * 4 + (NT)) * 1536); \
    BH = fb_[lane]; BM = fb_[lane + 64]; BL = fb_[lane + 128];             \
  } while (0)

#define MFMA12(NT, BH, BM, BL)                                             \
  do {                                                                     \
    acc[NT] = MFMA(Ah, BH, acc[NT], 0, 0, 0);                              \
    acc[NT] = MFMA(Ah, BM, acc[NT], 0, 0, 0);                              \
    acc[NT] = MFMA(Am, BH, acc[NT], 0, 0, 0);                              \
    acc[NT] = MFMA(Am, BM, acc[NT], 0, 0, 0);                              \
    acc[NT] = MFMA(Ah, BL, acc[NT], 0, 0, 0);                              \
    acc[NT] = MFMA(Al, BH, acc[NT], 0, 0, 0);                              \
  } while (0)

  // one ks step (KK = 0..3 compile-time within SC; R11 product order)
#define KS_BODY(S, KK, BUF)                                                \
  do {                                                                     \
    const int ks_ = (S) * 4 + (KK);                                        \
    short8 BhA, BmA, BlA, BhB, BmB, BlB;                                   \
    LOAD_B(ks_, 0, BhA, BmA, BlA);                                         \
    float4 c0 = *(const float4*)(lds + xrbase + (BUF) * XW + (KK) * 32);   \
    float4 c1 = *(const float4*)(lds + xrbase + (BUF) * XW + (KK) * 32 + 4);\
    short8 Ah, Am, Al;                                                     \
    cvt3(c0, c1, &Ah, &Am, &Al);                                           \
    LOAD_B(ks_, 1, BhB, BmB, BlB);                                         \
    MFMA12(0, BhA, BmA, BlA);                                              \
    LOAD_B(ks_, 2, BhA, BmA, BlA);                                         \
    MFMA12(1, BhB, BmB, BlB);                                              \
    LOAD_B(ks_, 3, BhB, BmB, BlB);                                         \
    MFMA12(2, BhA, BmA, BlA);                                              \
    MFMA12(3, BhB, BmB, BlB);                                              \
  } while (0)

  // superchunk body: wait for buf CUR (loads issued one SC ago; 4-ks slack),
  // issue next SC into CUR^1, compute 4 ks from CUR. Wave-private: NO barrier.
#define SC_BODY(S, CUR)                                                    \
  do {                                                                     \
    asm volatile("s_waitcnt vmcnt(0)" ::: "memory");                       \
    __builtin_amdgcn_sched_barrier(0);                                     \
    if ((S) + 1 < NSC) STAGE_X((S) + 1, (CUR) ^ 1);                        \
    KS_BODY(S, 0, CUR);                                                    \
    KS_BODY(S, 1, CUR);                                                    \
    KS_BODY(S, 2, CUR);                                                    \
    KS_BODY(S, 3, CUR);                                                    \
  } while (0)

  STAGE_X(0, 0);
  for (int s2 = 0; s2 < NSC / 2; ++s2) {
    SC_BODY(s2 * 2, 0);
    SC_BODY(s2 * 2 + 1, 1);
  }

  // ---- all waves done with x LDS; slab overlays it ----
  __syncthreads();
  float* slab = lds;
#pragma unroll
  for (int nt = 0; nt < 4; ++nt)
#pragma unroll
    for (int reg = 0; reg < 4; ++reg) {
      int row = w * 16 + (lane >> 4) * 4 + reg;
      int col = nt * 16 + (lane & 15);
      slab[row * SLAB + col] = acc[nt][reg];
    }
  __syncthreads();

  // ---------------- epilogue: wave 0, lane = row (R11 verbatim) -----------
  if (w == 0) {
    float a[NEXP];
#pragma unroll
    for (int n = 0; n < NEXP; ++n) a[n] = slab[lane * SLAB + n];

    unsigned long long sel = 0ull;
    int idx[TOPK];
    float selu[TOPK];
#pragma unroll
    for (int k = 0; k < TOPK; ++k) {
      float best = -INFINITY, bestu = 0.f;
      int bi = 0;
#pragma unroll
      for (int n = 0; n < NEXP; ++n) {
        float vb = a[n] + bias[n];
        bool taken = (sel >> n) & 1ull;
        vb = taken ? -INFINITY : vb;
        if (vb > best) { best = vb; bestu = a[n]; bi = n; }
      }
      sel |= 1ull << bi;
      idx[k] = bi;
      selu[k] = bestu;
    }

    float mx = selu[0];
#pragma unroll
    for (int k = 1; k < TOPK; ++k) mx = fmaxf(mx, selu[k]);
    float g[TOPK]; float gs = 0.f;
#pragma unroll
    for (int k = 0; k < TOPK; ++k) { g[k] = __expf(selu[k] - mx); gs += g[k]; }
    float ginv = 1.f / gs;

    float* grow = out + (row0 + lane) * NEXP;
#pragma unroll
    for (int n4 = 0; n4 < 16; ++n4) {
      float gv[4];
#pragma unroll
      for (int j = 0; j < 4; ++j) {
        int n = n4 * 4 + j;
        float v = 0.f;
#pragma unroll
        for (int k = 0; k < TOPK; ++k) v = (idx[k] == n) ? g[k] * ginv : v;
        gv[j] = v;
      }
      *(float4*)(grow + n4 * 4) = make_float4(gv[0], gv[1], gv[2], gv[3]);
    }

    float* irow = out + GOFF + (row0 + lane) * TOPK;
    *(float4*)(irow + 0) = make_float4((float)idx[0], (float)idx[1], (float)idx[2], (float)idx[3]);
    *(float4*)(irow + 4) = make_float4((float)idx[4], (float)idx[5], (float)idx[6], (float)idx[7]);

    float m2 = -INFINITY;
#pragma unroll
    for (int n = 0; n < NEXP; ++n) m2 = fmaxf(m2, a[n]);
    float s2 = 0.f;
#pragma unroll
    for (int n = 0; n < NEXP; ++n) s2 += __expf(a[n] - m2);
    float pinv = 1.f / s2;

    float myP = 0.f, myF = 0.f;
#pragma unroll
    for (int n = 0; n < NEXP; ++n) {
      float v = __expf(a[n] - m2) * pinv;
      v += __shfl_xor(v, 1);
      v += __shfl_xor(v, 2);
      v += __shfl_xor(v, 4);
      v += __shfl_xor(v, 8);
      v += __shfl_xor(v, 16);
      v += __shfl_xor(v, 32);
      unsigned long long b = __ballot((sel >> n) & 1ull);
      if (lane == n) { myP = v; myF = (float)__popcll(b); }
    }
    ws[(size_t)blockIdx.x * (2 * NEXP) + lane] = myF;
    ws[(size_t)blockIdx.x * (2 * NEXP) + NEXP + lane] = myP;
  }
}

// aux stage 1: 16 blocks, each reduces 64 block-partials (deterministic order)
__global__ __launch_bounds__(256) void router_aux1(
    const float* __restrict__ ws, float* __restrict__ ws2)
{
  __shared__ float sf[4][NEXP];
  __shared__ float sp[4][NEXP];
  int t = threadIdx.x;
  int n = t & 63, part = t >> 6;
  int b0 = blockIdx.x * 64;
  float f = 0.f, p = 0.f;
#pragma unroll 4
  for (int b = b0 + part; b < b0 + 64; b += 4) {
    f += ws[(size_t)b * (2 * NEXP) + n];
    p += ws[(size_t)b * (2 * NEXP) + NEXP + n];
  }
  sf[part][n] = f;
  sp[part][n] = p;
  __syncthreads();
  if (t < NEXP) {
    ws2[blockIdx.x * 128 + t]      = sf[0][t] + sf[1][t] + sf[2][t] + sf[3][t];
    ws2[blockIdx.x * 128 + 64 + t] = sp[0][t] + sp[1][t] + sp[2][t] + sp[3][t];
  }
}

// aux stage 2: 1 block of 64, fixed-order final reduce
__global__ __launch_bounds__(64) void router_aux2(
    const float* __restrict__ ws2, float* __restrict__ out)
{
  int t = threadIdx.x;
  float F = 0.f, P = 0.f;
#pragma unroll
  for (int g = 0; g < 16; ++g) {
    F += ws2[g * 128 + t];
    P += ws2[g * 128 + 64 + t];
  }
  float v = F * P;
  v += __shfl_xor(v, 1);
  v += __shfl_xor(v, 2);
  v += __shfl_xor(v, 4);
  v += __shfl_xor(v, 8);
  v += __shfl_xor(v, 16);
  v += __shfl_xor(v, 32);
  if (t == 0)
    out[AUX_OFF] = 0.01f * 64.f * v / (4294967296.0f /* 65536^2 */);
}

extern "C" void kernel_launch(void* const* d_in, const int* in_sizes, int n_in,
                              void* d_out, int out_size, void* d_ws, size_t ws_size,
                              hipStream_t stream) {
  const float* x = (const float*)d_in[0];
  const float* W = (const float*)d_in[1];
  const float* bias = (const float*)d_in[2];
  float* out = (float*)d_out;
  float* ws = (float*)d_ws;
  unsigned short* frag = (unsigned short*)(ws + WS_FRAG_OFF);
  float* ws2 = ws + WS2_OFF;
  router_prep<<<NKS, 256, 0, stream>>>(W, frag);
  router_main<<<NBLK, THREADS, 0, stream>>>(x, bias, frag, out, ws);
  router_aux1<<<16, 256, 0, stream>>>(ws, ws2);
  router_aux2<<<1, 64, 0, stream>>>(ws2, out);
}

// Round 15
// 214.466 us; speedup vs baseline: 1.2656x; 1.2656x over previous
//
#include <hip/hip_runtime.h>
#include <cstdint>
#include <cstddef>

typedef __attribute__((ext_vector_type(8))) short short8;
typedef __attribute__((ext_vector_type(4))) float f32x4;

#define B_ROWS 65536
#define DMODEL 2048
#define NEXP 64
#define TOPK 8
#define THREADS 256                      // 4 waves; wave = 16 rows x 64 experts
#define ROWS_PER_BLK 64
#define NBLK (B_ROWS / ROWS_PER_BLK)     // 1024 blocks
#define NKS (DMODEL / 32)                // 64 k-steps
#define NSC (NKS / 2)                    // 32 superchunks (2 ks, 256B/row)
#define XWAVE 2112                       // floats per wave: 2 bufs x 1056
#define XBUF 1056                        // 4 quad-blocks x 264
#define BBASE 8448                       // B region base (floats)
#define SLAB 67
#define GOFF ((size_t)B_ROWS * NEXP)
#define AUX_OFF (GOFF + (size_t)B_ROWS * TOPK)
#define WS_FRAG_OFF 131072
#define WS2_OFF 229376

#define GLOAD16(g, l)                                                      \
  __builtin_amdgcn_global_load_lds(                                       \
      (const __attribute__((address_space(1))) void*)(g),                 \
      (__attribute__((address_space(3))) void*)(l), 16, 0, 0)

// R9/R11-proven RNE bf16 helper
__device__ __forceinline__ unsigned short bf16_rne(float v, float* back) {
  unsigned u = __float_as_uint(v);
  unsigned r = (u + 0x7FFFu + ((u >> 16) & 1u)) >> 16;
  *back = __uint_as_float(r << 16);
  return (unsigned short)r;
}

// W -> bf16x3 B-fragments (R11 verbatim)
__global__ __launch_bounds__(256) void router_prep(
    const float* __restrict__ W, unsigned short* __restrict__ frag)
{
  const int ks = blockIdx.x;
  const int nt = threadIdx.x >> 6;
  const int lane = threadIdx.x & 63;
  const int krow = ks * 32 + (lane >> 4) * 8;
  const int col = nt * 16 + (lane & 15);
  short8 hv, mv, lv;
#pragma unroll
  for (int j = 0; j < 8; ++j) {
    float v = W[(size_t)(krow + j) * NEXP + col];
    float fh, fm, fl;
    unsigned short h = bf16_rne(v, &fh);
    float r = v - fh;
    unsigned short m = bf16_rne(r, &fm);
    float r2 = r - fm;
    unsigned short l = bf16_rne(r2, &fl);
    hv[j] = (short)h; mv[j] = (short)m; lv[j] = (short)l;
  }
  size_t base = (size_t)(ks * 4 + nt) * 1536 + lane * 8;
  *(short8*)(frag + base)        = hv;
  *(short8*)(frag + base + 512)  = mv;
  *(short8*)(frag + base + 1024) = lv;
}

// R11 cvt3 verbatim
__device__ __forceinline__ void cvt3(float4 a, float4 b,
                                     short8* H, short8* M, short8* L) {
  float f[8] = {a.x, a.y, a.z, a.w, b.x, b.y, b.z, b.w};
#pragma unroll
  for (int j = 0; j < 8; ++j) {
    float fh, fm, fl;
    unsigned short h = bf16_rne(f[j], &fh);
    float r = f[j] - fh;
    unsigned short m = bf16_rne(r, &fm);
    float r2 = r - fm;
    unsigned short l = bf16_rne(r2, &fl);
    (*H)[j] = (short)h; (*M)[j] = (short)m; (*L)[j] = (short)l;
  }
}

#define MFMA __builtin_amdgcn_mfma_f32_16x16x32_bf16

__global__ __launch_bounds__(THREADS, 2) void router_main(
    const float* __restrict__ x, const float* __restrict__ bias,
    const unsigned short* __restrict__ frag, float* __restrict__ out,
    float* __restrict__ ws)
{
  // LDS floats: x [4 waves][2 bufs][1056] = 8448; B [3 bufs][3072] = 9216.
  // Total 17664 (70.7 KB) -> 2 blocks/CU. Epilogue slab overlays x region.
  __shared__ __align__(16) float lds[BBASE + 3 * 3072];

  const int tid = threadIdx.x;
  const int lane = tid & 63;
  const int w = tid >> 6;
  const size_t row0 = (size_t)blockIdx.x * ROWS_PER_BLK;

  f32x4 acc[4];
#pragma unroll
  for (int nt = 0; nt < 4; ++nt) acc[nt] = (f32x4){0.f, 0.f, 0.f, 0.f};

  // ---- x staging geometry ----
  // instr i covers rows i*4..i*4+3: lane l -> row i*4+(l>>4); global float4
  // (l&15)^(l>>4) of the 16-f4 SC window (source swizzle; LDS dest linear).
  const float* xg = x + (row0 + (size_t)w * 16 + (lane >> 4)) * DMODEL
                  + (size_t)(((lane & 15) ^ (lane >> 4)) * 4);
  // read: row r=lane&15 -> quad i_=r>>2 (stride 264), sub s_=r&3 (stride 64);
  // slot for global f4 G is G^s_ (involution). G0=(lane>>4)*2 (+8 f4 if kk).
  const int i_ = (lane & 15) >> 2, s_ = (lane & 15) & 3;
  const int g0 = (lane >> 4) * 2;
  const int xrd = w * XWAVE + i_ * 264 + s_ * 64;
  const int o0 = ((g0) ^ s_) * 4;
  const int o1 = ((g0 + 1) ^ s_) * 4;

#define STAGE_X(SC, BUF)                                                   \
  do {                                                                     \
    _Pragma("unroll") for (int i = 0; i < 4; ++i)                          \
      GLOAD16(xg + (size_t)i * 4 * DMODEL + (SC) * 64,                     \
              lds + w * XWAVE + (BUF) * XBUF + i * 264);                   \
  } while (0)

#define STAGE_B(KS, BUF)                                                   \
  do {                                                                     \
    _Pragma("unroll") for (int j = 0; j < 3; ++j)                          \
      GLOAD16(frag + (size_t)(KS) * 6144 + (w * 3 + j) * 512 + lane * 8,   \
              lds + BBASE + (BUF) * 3072 + (w * 3 + j) * 256);             \
  } while (0)

#define COMPUTE(K)                                                         \
  do {                                                                     \
    const int b3_ = (K) % 3;                                               \
    const int kk_ = (K) & 1;                                               \
    const float* bb = lds + BBASE + b3_ * 3072;                            \
    short8 B[12];                                                          \
    _Pragma("unroll") for (int f = 0; f < 12; ++f)                         \
      B[f] = *(const short8*)(bb + f * 256 + lane * 4);                    \
    const float* xw = lds + xrd + (((K) >> 1) & 1) * XBUF + kk_ * 32;      \
    float4 c0 = *(const float4*)(xw + o0);                                 \
    float4 c1 = *(const float4*)(xw + o1);                                 \
    short8 Ah, Am, Al;                                                     \
    cvt3(c0, c1, &Ah, &Am, &Al);                                           \
    _Pragma("unroll") for (int nt = 0; nt < 4; ++nt) {                     \
      acc[nt] = MFMA(Ah, B[nt * 3 + 0], acc[nt], 0, 0, 0);                 \
      acc[nt] = MFMA(Ah, B[nt * 3 + 1], acc[nt], 0, 0, 0);                 \
      acc[nt] = MFMA(Am, B[nt * 3 + 0], acc[nt], 0, 0, 0);                 \
      acc[nt] = MFMA(Am, B[nt * 3 + 1], acc[nt], 0, 0, 0);                 \
      acc[nt] = MFMA(Ah, B[nt * 3 + 2], acc[nt], 0, 0, 0);                 \
      acc[nt] = MFMA(Al, B[nt * 3 + 0], acc[nt], 0, 0, 0);                 \
    }                                                                      \
  } while (0)

  // ITER: counted wait (never 0 mid-loop) + raw barrier, THEN issue (buffer
  // freed by the barrier), then compute. Even iters MUST issue B before X.
#define ITER(K, DO_B, DO_X, VM)                                            \
  do {                                                                     \
    asm volatile("s_waitcnt vmcnt(" #VM ")" ::: "memory");                 \
    __builtin_amdgcn_sched_barrier(0);                                     \
    __builtin_amdgcn_s_barrier();                                          \
    if (DO_B) STAGE_B((K) + 2, ((K) + 2) % 3);                             \
    if (DO_X) STAGE_X(((K) >> 1) + 1, (((K) >> 1) + 1) & 1);               \
    __builtin_amdgcn_sched_barrier(0);                                     \
    COMPUTE(K);                                                            \
  } while (0)

  // prologue: B(0), X(0), B(1)  (order matters for the k=0 count)
  STAGE_B(0, 0);
  STAGE_X(0, 0);
  STAGE_B(1, 1);

  for (int k2 = 0; k2 < 31; ++k2) {
    const int k = k2 * 2;
    ITER(k, true, true, 3);       // wait {B(k),X(sc)}; issue B(k+2), X(sc+1)
    ITER(k + 1, true, false, 7);  // wait {B(k+1)};    issue B(k+3)
  }
  ITER(62, false, false, 3);
  ITER(63, false, false, 0);

  // ---- slab overlays x region ----
  __syncthreads();
  float* slab = lds;
#pragma unroll
  for (int nt = 0; nt < 4; ++nt)
#pragma unroll
    for (int reg = 0; reg < 4; ++reg) {
      int row = w * 16 + (lane >> 4) * 4 + reg;
      int col = nt * 16 + (lane & 15);
      slab[row * SLAB + col] = acc[nt][reg];
    }
  __syncthreads();

  // ---------------- epilogue: wave 0, lane = row (R11 verbatim) -----------
  if (w == 0) {
    float a[NEXP];
#pragma unroll
    for (int n = 0; n < NEXP; ++n) a[n] = slab[lane * SLAB + n];

    unsigned long long sel = 0ull;
    int idx[TOPK];
    float selu[TOPK];
#pragma unroll
    for (int k = 0; k < TOPK; ++k) {
      float best = -INFINITY, bestu = 0.f;
      int bi = 0;
#pragma unroll
      for (int n = 0; n < NEXP; ++n) {
        float vb = a[n] + bias[n];
        bool taken = (sel >> n) & 1ull;
        vb = taken ? -INFINITY : vb;
        if (vb > best) { best = vb; bestu = a[n]; bi = n; }
      }
      sel |= 1ull << bi;
      idx[k] = bi;
      selu[k] = bestu;
    }

    float mx = selu[0];
#pragma unroll
    for (int k = 1; k < TOPK; ++k) mx = fmaxf(mx, selu[k]);
    float g[TOPK]; float gs = 0.f;
#pragma unroll
    for (int k = 0; k < TOPK; ++k) { g[k] = __expf(selu[k] - mx); gs += g[k]; }
    float ginv = 1.f / gs;

    float* grow = out + (row0 + lane) * NEXP;
#pragma unroll
    for (int n4 = 0; n4 < 16; ++n4) {
      float gv[4];
#pragma unroll
      for (int j = 0; j < 4; ++j) {
        int n = n4 * 4 + j;
        float v = 0.f;
#pragma unroll
        for (int k = 0; k < TOPK; ++k) v = (idx[k] == n) ? g[k] * ginv : v;
        gv[j] = v;
      }
      *(float4*)(grow + n4 * 4) = make_float4(gv[0], gv[1], gv[2], gv[3]);
    }

    float* irow = out + GOFF + (row0 + lane) * TOPK;
    *(float4*)(irow + 0) = make_float4((float)idx[0], (float)idx[1], (float)idx[2], (float)idx[3]);
    *(float4*)(irow + 4) = make_float4((float)idx[4], (float)idx[5], (float)idx[6], (float)idx[7]);

    float m2 = -INFINITY;
#pragma unroll
    for (int n = 0; n < NEXP; ++n) m2 = fmaxf(m2, a[n]);
    float s2 = 0.f;
#pragma unroll
    for (int n = 0; n < NEXP; ++n) s2 += __expf(a[n] - m2);
    float pinv = 1.f / s2;

    float myP = 0.f, myF = 0.f;
#pragma unroll
    for (int n = 0; n < NEXP; ++n) {
      float v = __expf(a[n] - m2) * pinv;
      v += __shfl_xor(v, 1);
      v += __shfl_xor(v, 2);
      v += __shfl_xor(v, 4);
      v += __shfl_xor(v, 8);
      v += __shfl_xor(v, 16);
      v += __shfl_xor(v, 32);
      unsigned long long b = __ballot((sel >> n) & 1ull);
      if (lane == n) { myP = v; myF = (float)__popcll(b); }
    }
    ws[(size_t)blockIdx.x * (2 * NEXP) + lane] = myF;
    ws[(size_t)blockIdx.x * (2 * NEXP) + NEXP + lane] = myP;
  }
}

// aux stage 1: 16 blocks x 64 block-partials (deterministic order)
__global__ __launch_bounds__(256) void router_aux1(
    const float* __restrict__ ws, float* __restrict__ ws2)
{
  __shared__ float sf[4][NEXP];
  __shared__ float sp[4][NEXP];
  int t = threadIdx.x;
  int n = t & 63, part = t >> 6;
  int b0 = blockIdx.x * 64;
  float f = 0.f, p = 0.f;
#pragma unroll 4
  for (int b = b0 + part; b < b0 + 64; b += 4) {
    f += ws[(size_t)b * (2 * NEXP) + n];
    p += ws[(size_t)b * (2 * NEXP) + NEXP + n];
  }
  sf[part][n] = f;
  sp[part][n] = p;
  __syncthreads();
  if (t < NEXP) {
    ws2[blockIdx.x * 128 + t]      = sf[0][t] + sf[1][t] + sf[2][t] + sf[3][t];
    ws2[blockIdx.x * 128 + 64 + t] = sp[0][t] + sp[1][t] + sp[2][t] + sp[3][t];
  }
}

// aux stage 2: fixed-order final reduce
__global__ __launch_bounds__(64) void router_aux2(
    const float* __restrict__ ws2, float* __restrict__ out)
{
  int t = threadIdx.x;
  float F = 0.f, P = 0.f;
#pragma unroll
  for (int g = 0; g < 16; ++g) {
    F += ws2[g * 128 + t];
    P += ws2[g * 128 + 64 + t];
  }
  float v = F * P;
  v += __shfl_xor(v, 1);
  v += __shfl_xor(v, 2);
  v += __shfl_xor(v, 4);
  v += __shfl_xor(v, 8);
  v += __shfl_xor(v, 16);
  v += __shfl_xor(v, 32);
  if (t == 0)
    out[AUX_OFF] = 0.01f * 64.f * v / (4294967296.0f /* 65536^2 */);
}

extern "C" void kernel_launch(void* const* d_in, const int* in_sizes, int n_in,
                              void* d_out, int out_size, void* d_ws, size_t ws_size,
                              hipStream_t stream) {
  const float* x = (const float*)d_in[0];
  const float* W = (const float*)d_in[1];
  const float* bias = (const float*)d_in[2];
  float* out = (float*)d_out;
  float* ws = (float*)d_ws;
  unsigned short* frag = (unsigned short*)(ws + WS_FRAG_OFF);
  float* ws2 = ws + WS2_OFF;
  router_prep<<<NKS, 256, 0, stream>>>(W, frag);
  router_main<<<NBLK, THREADS, 0, stream>>>(x, bias, frag, out, ws);
  router_aux1<<<16, 256, 0, stream>>>(ws, ws2);
  router_aux2<<<1, 64, 0, stream>>>(ws2, out);
}

// Round 16
// 206.272 us; speedup vs baseline: 1.3158x; 1.0397x over previous
//
#include <hip/hip_runtime.h>
#include <cstdint>
#include <cstddef>

typedef __attribute__((ext_vector_type(8))) short short8;
typedef __attribute__((ext_vector_type(4))) float f32x4;

#define B_ROWS 65536
#define DMODEL 2048
#define NEXP 64
#define TOPK 8
#define THREADS 512                      // 8 waves; wave = 16 rows x 64 experts
#define ROWS_PER_BLK 128
#define NBLK (B_ROWS / ROWS_PER_BLK)     // 512 blocks = 2 per CU (16 waves/CU)
#define NKS (DMODEL / 32)                // 64 k-steps
#define NITER (NKS / 2)                  // 32 iterations of 2 ks
#define SLAB 67
#define GOFF ((size_t)B_ROWS * NEXP)
#define AUX_OFF (GOFF + (size_t)B_ROWS * TOPK)
#define WS_FRAG_OFF 131072
#define WS2_OFF 229376

#define GLOAD16(g, l)                                                      \
  __builtin_amdgcn_global_load_lds(                                       \
      (const __attribute__((address_space(1))) void*)(g),                 \
      (__attribute__((address_space(3))) void*)(l), 16, 0, 0)

// R9/R11-proven RNE bf16 helper
__device__ __forceinline__ unsigned short bf16_rne(float v, float* back) {
  unsigned u = __float_as_uint(v);
  unsigned r = (u + 0x7FFFu + ((u >> 16) & 1u)) >> 16;
  *back = __uint_as_float(r << 16);
  return (unsigned short)r;
}

// W -> bf16x3 B-fragments (R11 verbatim)
__global__ __launch_bounds__(256) void router_prep(
    const float* __restrict__ W, unsigned short* __restrict__ frag)
{
  const int ks = blockIdx.x;
  const int nt = threadIdx.x >> 6;
  const int lane = threadIdx.x & 63;
  const int krow = ks * 32 + (lane >> 4) * 8;
  const int col = nt * 16 + (lane & 15);
  short8 hv, mv, lv;
#pragma unroll
  for (int j = 0; j < 8; ++j) {
    float v = W[(size_t)(krow + j) * NEXP + col];
    float fh, fm, fl;
    unsigned short h = bf16_rne(v, &fh);
    float r = v - fh;
    unsigned short m = bf16_rne(r, &fm);
    float r2 = r - fm;
    unsigned short l = bf16_rne(r2, &fl);
    hv[j] = (short)h; mv[j] = (short)m; lv[j] = (short)l;
  }
  size_t base = (size_t)(ks * 4 + nt) * 1536 + lane * 8;
  *(short8*)(frag + base)        = hv;
  *(short8*)(frag + base + 512)  = mv;
  *(short8*)(frag + base + 1024) = lv;
}

// R11 cvt3 verbatim
__device__ __forceinline__ void cvt3(float4 a, float4 b,
                                     short8* H, short8* M, short8* L) {
  float f[8] = {a.x, a.y, a.z, a.w, b.x, b.y, b.z, b.w};
#pragma unroll
  for (int j = 0; j < 8; ++j) {
    float fh, fm, fl;
    unsigned short h = bf16_rne(f[j], &fh);
    float r = f[j] - fh;
    unsigned short m = bf16_rne(r, &fm);
    float r2 = r - fm;
    unsigned short l = bf16_rne(r2, &fl);
    (*H)[j] = (short)h; (*M)[j] = (short)m; (*L)[j] = (short)l;
  }
}

#define MFMA __builtin_amdgcn_mfma_f32_16x16x32_bf16

__global__ __launch_bounds__(THREADS, 4) void router_main(
    const float* __restrict__ x, const float* __restrict__ bias,
    const unsigned short* __restrict__ frag, float* __restrict__ out,
    float* __restrict__ ws)
{
  // LDS: B pair double-buffer 2 x 6144 floats = 48KB.
  // Epilogue slab [128][67]+red (8832 fl) overlays it after a barrier.
  __shared__ __align__(16) float lds[2 * 6144];

  const int tid = threadIdx.x;
  const int lane = tid & 63;
  const int w = tid >> 6;
  const size_t row0 = (size_t)blockIdx.x * ROWS_PER_BLK;

  f32x4 acc[4];
#pragma unroll
  for (int nt = 0; nt < 4; ++nt) acc[nt] = (f32x4){0.f, 0.f, 0.f, 0.f};

  // A-side (R9-proven): lane l -> row (l&15), k-cols (l>>4)*8..+7
  const float* xp = x + (row0 + (size_t)w * 16 + (lane & 15)) * DMODEL
                  + (lane >> 4) * 8;

  // B pair g = ks{2g,2g+1} = 24KB = 24 chunks of 1KB; wave w stages 3.
#define STAGE_BPAIR(G, BUF)                                                \
  do {                                                                     \
    _Pragma("unroll") for (int j = 0; j < 3; ++j)                          \
      GLOAD16(frag + (size_t)(G) * 12288 + (w * 3 + j) * 512 + lane * 8,   \
              lds + (BUF) * 6144 + (w * 3 + j) * 256);                     \
  } while (0)

  // staggered B regs (R9 pattern), ds_read_b128 conflict-free
#define LOAD_BL(BB, NT, BH, BM, BL)                                        \
  do {                                                                     \
    const float* p_ = (BB) + (NT) * 768 + lane * 4;                        \
    BH = *(const short8*)(p_);                                             \
    BM = *(const short8*)(p_ + 256);                                       \
    BL = *(const short8*)(p_ + 512);                                       \
  } while (0)

#define MFMA12(NT, BH, BM, BL)                                             \
  do {                                                                     \
    acc[NT] = MFMA(Ah, BH, acc[NT], 0, 0, 0);                              \
    acc[NT] = MFMA(Ah, BM, acc[NT], 0, 0, 0);                              \
    acc[NT] = MFMA(Am, BH, acc[NT], 0, 0, 0);                              \
    acc[NT] = MFMA(Am, BM, acc[NT], 0, 0, 0);                              \
    acc[NT] = MFMA(Ah, BL, acc[NT], 0, 0, 0);                              \
    acc[NT] = MFMA(Al, BH, acc[NT], 0, 0, 0);                              \
  } while (0)

  // one ks: R11 product order per nt
#define COMPUTE_KS(G, KK, C0, C1)                                          \
  do {                                                                     \
    const float* bb = lds + ((G) & 1) * 6144 + (KK) * 3072;                \
    short8 Ah, Am, Al;                                                     \
    cvt3(C0, C1, &Ah, &Am, &Al);                                           \
    short8 BhA, BmA, BlA, BhB, BmB, BlB;                                   \
    LOAD_BL(bb, 0, BhA, BmA, BlA);                                         \
    LOAD_BL(bb, 1, BhB, BmB, BlB);                                         \
    MFMA12(0, BhA, BmA, BlA);                                              \
    LOAD_BL(bb, 2, BhA, BmA, BlA);                                         \
    MFMA12(1, BhB, BmB, BlB);                                              \
    LOAD_BL(bb, 3, BhB, BmB, BlB);                                         \
    MFMA12(2, BhA, BmA, BlA);                                              \
    MFMA12(3, BhB, BmB, BlB);                                              \
  } while (0)

#define XLOAD(G, V0, V1, V2, V3)                                           \
  do {                                                                     \
    V0 = *(const float4*)(xp + (G) * 64);                                  \
    V1 = *(const float4*)(xp + (G) * 64 + 4);                              \
    V2 = *(const float4*)(xp + (G) * 64 + 32);                             \
    V3 = *(const float4*)(xp + (G) * 64 + 36);                             \
  } while (0)

  // iter top: retire own B-trio (keep x set in flight), sync, issue next.
#define ITER_HEAD(G)                                                       \
  do {                                                                     \
    asm volatile("s_waitcnt vmcnt(4)" ::: "memory");                       \
    __builtin_amdgcn_sched_barrier(0);                                     \
    __builtin_amdgcn_s_barrier();                                          \
  } while (0)

  float4 a0, a1, a2, a3, b0, b1, b2, b3;
  STAGE_BPAIR(0, 0);
  XLOAD(0, a0, a1, a2, a3);

  for (int g2 = 0; g2 < 16; ++g2) {
    {
      const int g = 2 * g2;            // even iter: cur = A, next -> B
      ITER_HEAD(g);
      STAGE_BPAIR(g + 1, (g + 1) & 1); // g+1 <= 31 always here
      XLOAD(g + 1, b0, b1, b2, b3);
      COMPUTE_KS(g, 0, a0, a1);
      COMPUTE_KS(g, 1, a2, a3);
    }
    {
      const int g = 2 * g2 + 1;        // odd iter: cur = B, next -> A
      ITER_HEAD(g);
      if (g + 1 < NITER) {
        STAGE_BPAIR(g + 1, (g + 1) & 1);
        XLOAD(g + 1, a0, a1, a2, a3);
      }
      COMPUTE_KS(g, 0, b0, b1);
      COMPUTE_KS(g, 1, b2, b3);
    }
  }

  // ---- slab overlays B region ----
  __syncthreads();
  float* slab = lds;
#pragma unroll
  for (int nt = 0; nt < 4; ++nt)
#pragma unroll
    for (int reg = 0; reg < 4; ++reg) {
      int row = w * 16 + (lane >> 4) * 4 + reg;
      int col = nt * 16 + (lane & 15);
      slab[row * SLAB + col] = acc[nt][reg];
    }
  __syncthreads();

  // ---------------- epilogue: waves 0-1, lane = row (R8-proven) -----------
  float* redF = lds + ROWS_PER_BLK * SLAB;   // 128 floats
  float* redP = redF + 128;                  // 128 floats

  if (w < 2) {
    const int row = w * 64 + lane;
    float a[NEXP];
#pragma unroll
    for (int n = 0; n < NEXP; ++n) a[n] = slab[row * SLAB + n];

    unsigned long long sel = 0ull;
    int idx[TOPK];
    float selu[TOPK];
#pragma unroll
    for (int k = 0; k < TOPK; ++k) {
      float best = -INFINITY, bestu = 0.f;
      int bi = 0;
#pragma unroll
      for (int n = 0; n < NEXP; ++n) {
        float vb = a[n] + bias[n];
        bool taken = (sel >> n) & 1ull;
        vb = taken ? -INFINITY : vb;
        if (vb > best) { best = vb; bestu = a[n]; bi = n; }
      }
      sel |= 1ull << bi;
      idx[k] = bi;
      selu[k] = bestu;
    }

    float mx = selu[0];
#pragma unroll
    for (int k = 1; k < TOPK; ++k) mx = fmaxf(mx, selu[k]);
    float g[TOPK]; float gs = 0.f;
#pragma unroll
    for (int k = 0; k < TOPK; ++k) { g[k] = __expf(selu[k] - mx); gs += g[k]; }
    float ginv = 1.f / gs;

    float* grow = out + (row0 + row) * NEXP;
#pragma unroll
    for (int n4 = 0; n4 < 16; ++n4) {
      float gv[4];
#pragma unroll
      for (int j = 0; j < 4; ++j) {
        int n = n4 * 4 + j;
        float v = 0.f;
#pragma unroll
        for (int k = 0; k < TOPK; ++k) v = (idx[k] == n) ? g[k] * ginv : v;
        gv[j] = v;
      }
      *(float4*)(grow + n4 * 4) = make_float4(gv[0], gv[1], gv[2], gv[3]);
    }

    float* irow = out + GOFF + (row0 + row) * TOPK;
    *(float4*)(irow + 0) = make_float4((float)idx[0], (float)idx[1], (float)idx[2], (float)idx[3]);
    *(float4*)(irow + 4) = make_float4((float)idx[4], (float)idx[5], (float)idx[6], (float)idx[7]);

    float m2 = -INFINITY;
#pragma unroll
    for (int n = 0; n < NEXP; ++n) m2 = fmaxf(m2, a[n]);
    float s2 = 0.f;
#pragma unroll
    for (int n = 0; n < NEXP; ++n) s2 += __expf(a[n] - m2);
    float pinv = 1.f / s2;

    float myP = 0.f, myF = 0.f;
#pragma unroll
    for (int n = 0; n < NEXP; ++n) {
      float v = __expf(a[n] - m2) * pinv;
      v += __shfl_xor(v, 1);
      v += __shfl_xor(v, 2);
      v += __shfl_xor(v, 4);
      v += __shfl_xor(v, 8);
      v += __shfl_xor(v, 16);
      v += __shfl_xor(v, 32);
      unsigned long long b = __ballot((sel >> n) & 1ull);
      if (lane == n) { myP = v; myF = (float)__popcll(b); }
    }
    redF[w * 64 + lane] = myF;
    redP[w * 64 + lane] = myP;
  }

  __syncthreads();
  if (tid < NEXP) {
    float F = redF[tid] + redF[64 + tid];
    float P = redP[tid] + redP[64 + tid];
    ws[(size_t)blockIdx.x * (2 * NEXP) + tid] = F;
    ws[(size_t)blockIdx.x * (2 * NEXP) + NEXP + tid] = P;
  }
}

// aux stage 1: 16 blocks x 32 block-partials (deterministic order)
__global__ __launch_bounds__(256) void router_aux1(
    const float* __restrict__ ws, float* __restrict__ ws2)
{
  __shared__ float sf[4][NEXP];
  __shared__ float sp[4][NEXP];
  int t = threadIdx.x;
  int n = t & 63, part = t >> 6;
  int b0 = blockIdx.x * 32;
  float f = 0.f, p = 0.f;
#pragma unroll 4
  for (int b = b0 + part; b < b0 + 32; b += 4) {
    f += ws[(size_t)b * (2 * NEXP) + n];
    p += ws[(size_t)b * (2 * NEXP) + NEXP + n];
  }
  sf[part][n] = f;
  sp[part][n] = p;
  __syncthreads();
  if (t < NEXP) {
    ws2[blockIdx.x * 128 + t]      = sf[0][t] + sf[1][t] + sf[2][t] + sf[3][t];
    ws2[blockIdx.x * 128 + 64 + t] = sp[0][t] + sp[1][t] + sp[2][t] + sp[3][t];
  }
}

// aux stage 2: fixed-order final reduce
__global__ __launch_bounds__(64) void router_aux2(
    const float* __restrict__ ws2, float* __restrict__ out)
{
  int t = threadIdx.x;
  float F = 0.f, P = 0.f;
#pragma unroll
  for (int g = 0; g < 16; ++g) {
    F += ws2[g * 128 + t];
    P += ws2[g * 128 + 64 + t];
  }
  float v = F * P;
  v += __shfl_xor(v, 1);
  v += __shfl_xor(v, 2);
  v += __shfl_xor(v, 4);
  v += __shfl_xor(v, 8);
  v += __shfl_xor(v, 16);
  v += __shfl_xor(v, 32);
  if (t == 0)
    out[AUX_OFF] = 0.01f * 64.f * v / (4294967296.0f /* 65536^2 */);
}

extern "C" void kernel_launch(void* const* d_in, const int* in_sizes, int n_in,
                              void* d_out, int out_size, void* d_ws, size_t ws_size,
                              hipStream_t stream) {
  const float* x = (const float*)d_in[0];
  const float* W = (const float*)d_in[1];
  const float* bias = (const float*)d_in[2];
  float* out = (float*)d_out;
  float* ws = (float*)d_ws;
  unsigned short* frag = (unsigned short*)(ws + WS_FRAG_OFF);
  float* ws2 = ws + WS2_OFF;
  router_prep<<<NKS, 256, 0, stream>>>(W, frag);
  router_main<<<NBLK, THREADS, 0, stream>>>(x, bias, frag, out, ws);
  router_aux1<<<16, 256, 0, stream>>>(ws, ws2);
  router_aux2<<<1, 64, 0, stream>>>(ws2, out);
}